// Round 6
// baseline (259.963 us; speedup 1.0000x reference)
//
#include <hip/hip_runtime.h>
#include <hip/hip_bf16.h>
#include <stdint.h>

// GCN fused: out = relu(A @ (H @ W^T) + b),  B=8, N=2048, L=4, D=256.
// pre_kernel (merged): blocks [0,1024) HWT = H@W^T bf16 transposed, LDS
// XOR-swizzled both sides; blocks [1024,3072) A fp32->bf16 convert.
// gemm8p: 256x256 tile, BK=64, 8 waves, 4 FAT phases/iter (32 MFMA each),
// frag reads one phase ahead, exact-counted vmcnt(0) (only the 8 gl16 of the
// buffer being waited on are in flight), 4 barriers/iter WAR/RAW structure.

typedef __bf16 bf16;
typedef __attribute__((ext_vector_type(8))) __bf16 bf16x8;
typedef __attribute__((ext_vector_type(4))) __bf16 bf16x4;
typedef __attribute__((ext_vector_type(4))) float f32x4;

#define B_  8
#define N_  2048
#define L_  4
#define D_  256
#define LD_ 1024
#define BK  64
#define NT  (N_ / BK)   // 32 K-tiles
#define NI  (NT / 2)    // 16 iterations

__device__ __forceinline__ void gl16(const char* g, char* l) {
  __builtin_amdgcn_global_load_lds((const __attribute__((address_space(1))) void*)g,
                                   (__attribute__((address_space(3))) void*)l, 16, 0, 0);
}

__device__ inline void cvt8(const float* __restrict__ s, bf16x8* o) {
  float4 x = ((const float4*)s)[0];
  float4 y = ((const float4*)s)[1];
  (*o)[0] = (bf16)x.x; (*o)[1] = (bf16)x.y; (*o)[2] = (bf16)x.z; (*o)[3] = (bf16)x.w;
  (*o)[4] = (bf16)y.x; (*o)[5] = (bf16)y.y; (*o)[6] = (bf16)y.z; (*o)[7] = (bf16)y.w;
}

// ---------------- kernel 1: merged pre-pass ----------------
// blocks [0,1024): HWT_T[b][l*256+e][m] = sum_d H[b][m][l][d]*W[e][d]  (bf16)
// blocks [1024,3072): A fp32 -> bf16 grid-stride convert
__global__ __launch_bounds__(256) void pre_kernel(const float* __restrict__ H,
                                                  const float* __restrict__ Wm,
                                                  const float* __restrict__ A,
                                                  bf16* __restrict__ outT,
                                                  bf16* __restrict__ a16) {
  __shared__ __attribute__((aligned(16))) char Ah[128 * 128];
  __shared__ __attribute__((aligned(16))) char Wt[128 * 128];

  if (blockIdx.x >= 1024) {
    // ---- cvt role ----
    const int n8 = (int)((size_t)B_ * N_ * N_ / 8);
    int i = (blockIdx.x - 1024) * 256 + threadIdx.x;
    for (; i < n8; i += 2048 * 256) {
      bf16x8 o;
      cvt8(A + (size_t)i * 8, &o);
      *(bf16x8*)(a16 + (size_t)i * 8) = o;
    }
    return;
  }

  // ---- hwt role ----
  const int bid = blockIdx.x;
  const int b   = bid >> 7;
  const int rem = bid & 127;
  const int te  = rem & 1;
  const int tr  = rem >> 1;
  const int r0  = tr * 128;
  const int e0  = te * 128;

  const int t    = threadIdx.x;
  const int lane = t & 63;
  const int wave = t >> 6;
  const int wr = wave >> 1, wc = wave & 1;
  const int l15 = lane & 15;
  const int cg  = lane >> 4;

  const f32x4 zero = {0.f, 0.f, 0.f, 0.f};
  f32x4 acc[4][4];
  for (int m = 0; m < 4; ++m)
    for (int n = 0; n < 4; ++n) acc[m][n] = zero;

  const float* Hb = H + (size_t)b * (N_ * L_ * D_);
  const int mrow = t >> 3;          // 0..31
  const int colb = (t & 7) * 8;
  // swizzled write byte offset: row = (t>>3)+i*32, slot = (t&7)^(row&7)
  const int woff = (t >> 3) * 128 + (((t & 7) ^ ((t >> 3) & 7)) << 4);

  for (int k0 = 0; k0 < D_; k0 += 64) {
#pragma unroll
    for (int i = 0; i < 4; ++i) {
      const int r_local = mrow * 4 + i;     // l = i, m_local = mrow
      bf16x8 oa, ow;
      cvt8(Hb + (size_t)(r0 + r_local) * D_ + k0 + colb, &oa);
      const int erow = i * 32 + mrow;
      cvt8(Wm + (size_t)(e0 + erow) * D_ + k0 + colb, &ow);
      *(bf16x8*)(Ah + woff + i * 4096) = oa;
      *(bf16x8*)(Wt + woff + i * 4096) = ow;
    }
    __syncthreads();
#pragma unroll
    for (int kk = 0; kk < 2; ++kk) {
      bf16x8 af[4], bg[4];
#pragma unroll
      for (int m = 0; m < 4; ++m) {
        const int row = wr * 64 + m * 16 + l15;
        af[m] = *(const bf16x8*)&Ah[row * 128 + (((kk * 4 + cg) ^ (row & 7)) << 4)];
      }
#pragma unroll
      for (int n = 0; n < 4; ++n) {
        const int row = wc * 64 + n * 16 + l15;
        bg[n] = *(const bf16x8*)&Wt[row * 128 + (((kk * 4 + cg) ^ (row & 7)) << 4)];
      }
#pragma unroll
      for (int m = 0; m < 4; ++m)
#pragma unroll
        for (int n = 0; n < 4; ++n)
          acc[m][n] = __builtin_amdgcn_mfma_f32_16x16x32_bf16(af[m], bg[n], acc[m][n], 0, 0, 0);
    }
    __syncthreads();
  }

  bf16* ob = outT + (size_t)b * (LD_ * N_);
  const int m0 = tr * 32;
#pragma unroll
  for (int m16 = 0; m16 < 4; ++m16) {
    const int qrow = wr * 64 + m16 * 16 + (cg << 2);
    const int l  = qrow >> 5;
    const int ml = qrow & 31;
#pragma unroll
    for (int n = 0; n < 4; ++n) {
      const int e = e0 + wc * 64 + n * 16 + l15;
      bf16x4 v;
      v[0] = (bf16)acc[m16][n][0]; v[1] = (bf16)acc[m16][n][1];
      v[2] = (bf16)acc[m16][n][2]; v[3] = (bf16)acc[m16][n][3];
      *(bf16x4*)&ob[(size_t)(l * 256 + e) * N_ + m0 + ml] = v;
    }
  }
}

// ---------------- kernel 2: 256x256-tile 4-fat-phase GEMM ----------------
// out[b][n][c] = relu(sum_m A16[b][n][m] * HWT[b][c][m] + bias[c&255])
__global__ __launch_bounds__(512, 2) void gemm8p_kernel(
    const bf16* __restrict__ A16, const bf16* __restrict__ HWT,
    const float* __restrict__ bias, float* __restrict__ out) {

  __shared__ __attribute__((aligned(128))) char smem[131072];

  // T1: 256 blocks % 8 == 0 -> xcd = batch
  const int bid = blockIdx.x;
  const int lg  = (bid & 7) * 32 + (bid >> 3);
  const int b   = lg >> 5;
  const int tn  = (lg >> 2) & 7;   // M tile (output rows, n-dim)
  const int tc  = lg & 3;          // N tile (output cols, c-dim)
  const int n0  = tn * 256;
  const int c0  = tc * 256;

  const int t    = threadIdx.x;
  const int lane = t & 63;
  const int w    = t >> 6;
  const int wm   = w >> 2;   // 0..1
  const int wn   = w & 3;    // 0..3
  const int l15  = lane & 15;
  const int cg   = lane >> 4;
  const int sl0  = cg ^ (lane & 7);     // swizzled 16B-slot for kk=0

  const char* Ab = (const char*)(A16 + (size_t)b * N_ * N_);
  const char* Hb = (const char*)(HWT + (size_t)b * LD_ * N_);
  const int  grow  = t >> 3;                       // 0..63
  const int  gslot = ((t & 7) ^ (grow & 7)) << 4;  // pre-swizzled source slot
  const char* pA = Ab + (size_t)(n0 + grow) * (N_ * 2) + gslot;
  const char* pB = Hb + (size_t)(c0 + grow) * (N_ * 2) + gslot;
  char* lbase = (char*)smem + t * 16;

#define STAGE(buf, isB, half, kt) do {                                        \
    const char* gp_ = ((isB) ? pB : pA) + (size_t)((half) * 128) * (N_ * 2)   \
                      + (size_t)(kt) * (BK * 2);                              \
    char* lp_ = lbase + (buf) * 65536 + (isB) * 32768 + (half) * 16384;       \
    gl16(gp_, lp_);                                                           \
    gl16(gp_ + (size_t)64 * (N_ * 2), lp_ + 8192);                            \
  } while (0)

#define STAGE4(buf, kt) do {                                                  \
    STAGE(buf, 0, 0, kt); STAGE(buf, 0, 1, kt);                               \
    STAGE(buf, 1, 0, kt); STAGE(buf, 1, 1, kt);                               \
  } while (0)

#define LDA(buf, mh, fm, kk)                                                  \
  (*(const bf16x8*)(smem + (buf) * 65536 +                                    \
      (wm * 128 + (mh) * 64 + (fm) * 16 + l15) * 128 +                        \
      ((sl0 ^ ((kk) * 4)) << 4)))

#define LDB(buf, fn, kk)                                                      \
  (*(const bf16x8*)(smem + (buf) * 65536 + 32768 +                            \
      (wn * 64 + (fn) * 16 + l15) * 128 +                                     \
      ((sl0 ^ ((kk) * 4)) << 4)))

#define RD_A(dst, buf, mh)                                                    \
  _Pragma("unroll")                                                           \
  for (int f_ = 0; f_ < 8; ++f_) dst[f_] = LDA(buf, mh, f_ >> 1, f_ & 1);

#define RD_B(dst, buf)                                                        \
  _Pragma("unroll")                                                           \
  for (int f_ = 0; f_ < 8; ++f_) dst[f_] = LDB(buf, f_ >> 1, f_ & 1);

// 32 MFMA: full K=64 (both kk) for one mh half. A8[fm*2+kk], B8[fn*2+kk].
#define MFMA32(base, A8, B8) do {                                             \
    __builtin_amdgcn_s_setprio(1);                                            \
    _Pragma("unroll")                                                         \
    for (int kk_ = 0; kk_ < 2; ++kk_)                                         \
      _Pragma("unroll")                                                       \
      for (int fm_ = 0; fm_ < 4; ++fm_)                                       \
        _Pragma("unroll")                                                     \
        for (int fn_ = 0; fn_ < 4; ++fn_)                                     \
          acc[(base) + fm_][fn_] = __builtin_amdgcn_mfma_f32_16x16x32_bf16(   \
              A8[fm_ * 2 + kk_], B8[fn_ * 2 + kk_], acc[(base) + fm_][fn_],   \
              0, 0, 0);                                                       \
    __builtin_amdgcn_s_setprio(0);                                            \
    __builtin_amdgcn_sched_barrier(0);                                        \
  } while (0)

#define BARRIER() do { __builtin_amdgcn_s_barrier();                          \
                       asm volatile("" ::: "memory"); } while (0)
#define VMCNT0_BAR() do {                                                     \
    asm volatile("s_waitcnt vmcnt(0)" ::: "memory");                          \
    __builtin_amdgcn_sched_barrier(0);                                        \
    BARRIER(); } while (0)

  f32x4 acc[8][4];
#pragma unroll
  for (int i_ = 0; i_ < 8; ++i_)
#pragma unroll
    for (int j_ = 0; j_ < 4; ++j_) acc[i_][j_] = (f32x4){0.f, 0.f, 0.f, 0.f};

  bf16x8 aP[8], aQ[8], bP[8], bQ[8];

  // prologue: buf0 <- kt0 fully; prime aP (mh0) + bP
  STAGE4(0, 0);
  VMCNT0_BAR();
  RD_A(aP, 0, 0);
  RD_B(bP, 0);

#pragma unroll 1
  for (int i = 0; i < NI; ++i) {
    const int kt1 = 2 * i + 1;
    const int kt2 = (2 * i + 2 < NT) ? 2 * i + 2 : NT - 2;  // clamp: tail stage unused

    // Q1: reads aQ<-A(buf0,mh1); stage buf1<-kt1; MFMA(buf0,mh0)=aPxbP
    RD_A(aQ, 0, 1);
    STAGE4(1, kt1);
    MFMA32(0, aP, bP);

    // Q2: [buf1 ready] vmcnt0+BAR; reads aP<-A(buf1,mh0), bQ<-B(buf1);
    //     MFMA(buf0,mh1)=aQxbP; BAR [all buf0 reads drained -> Q3 restage ok]
    VMCNT0_BAR();
    RD_A(aP, 1, 0);
    RD_B(bQ, 1);
    MFMA32(4, aQ, bP);
    BARRIER();

    // Q3: reads aQ<-A(buf1,mh1); stage buf0<-kt2; MFMA(buf1,mh0)=aPxbQ
    RD_A(aQ, 1, 1);
    STAGE4(0, kt2);
    MFMA32(0, aP, bQ);

    // Q4: [buf0' ready] vmcnt0+BAR; reads aP<-A(buf0',mh0), bP<-B(buf0');
    //     MFMA(buf1,mh1)=aQxbQ; BAR [all buf1 reads drained -> next Q1 ok]
    VMCNT0_BAR();
    RD_A(aP, 0, 0);
    RD_B(bP, 0);
    MFMA32(4, aQ, bQ);
    BARRIER();
  }

  // epilogue: + bias, relu, fp32 store
  float* ob = out + (size_t)b * N_ * LD_;
  const int orow0 = n0 + wm * 128 + cg * 4;
  const int ocol0 = c0 + wn * 64 + l15;
#pragma unroll
  for (int mh = 0; mh < 2; ++mh)
#pragma unroll
    for (int fm = 0; fm < 4; ++fm) {
      const int r = orow0 + mh * 64 + fm * 16;
#pragma unroll
      for (int fn = 0; fn < 4; ++fn) {
        const int c = ocol0 + fn * 16;
        const float bv = bias[c & 255];
        const f32x4 v = acc[mh * 4 + fm][fn];
#pragma unroll
        for (int j = 0; j < 4; ++j) {
          const float x = v[j] + bv;
          ob[(size_t)(r + j) * LD_ + c] = x > 0.f ? x : 0.f;
        }
      }
    }
#undef STAGE
#undef STAGE4
#undef LDA
#undef LDB
#undef RD_A
#undef RD_B
#undef MFMA32
#undef BARRIER
#undef VMCNT0_BAR
}

extern "C" void kernel_launch(void* const* d_in, const int* in_sizes, int n_in,
                              void* d_out, int out_size, void* d_ws, size_t ws_size,
                              hipStream_t stream) {
  const float* H    = (const float*)d_in[0];   // prop_state (B,N,L,D)
  const float* A    = (const float*)d_in[1];   // (B,N,N)
  const float* Wm   = (const float*)d_in[2];   // (D,D)
  const float* bias = (const float*)d_in[3];   // (D,)
  float* out = (float*)d_out;

  const size_t hwt_bytes = (size_t)B_ * LD_ * N_ * sizeof(bf16);  // 33.5 MB
  const size_t a16_bytes = (size_t)B_ * N_ * N_ * sizeof(bf16);   // 67.1 MB
  if (ws_size < hwt_bytes + a16_bytes) return;  // ws proven sufficient in R1

  bf16* hwt = (bf16*)d_ws;
  bf16* a16 = (bf16*)((char*)d_ws + hwt_bytes);

  pre_kernel<<<dim3(3072), dim3(256), 0, stream>>>(H, Wm, A, hwt, a16);
  gemm8p_kernel<<<dim3(256), dim3(512), 0, stream>>>(a16, hwt, bias, out);
}

// Round 7
// 139.658 us; speedup vs baseline: 1.8614x; 1.8614x over previous
//
#include <hip/hip_runtime.h>
#include <hip/hip_bf16.h>
#include <stdint.h>

// GCN fused: out = relu(A @ (H @ W^T) + b),  B=8, N=2048, L=4, D=256.
// hwt_kernel: HWT = H@W^T -> bf16 transposed (k-contiguous), swizzled LDS.
// gemm_f32a: 256x256 tile, BK=32, 8 waves. A staged as RAW FP32 via
// global_load_lds (no cvt pre-pass, no reg staging), converted to bf16 at
// LDS->reg fragment read. B staged bf16 via global_load_lds. Double-buffered,
// 4 phases/iter (16 MFMA each), exact-counted vmcnt(6), 4 barriers/iter.
// LDS: A 2x32KB fp32 + B 2x16KB bf16 = 96 KB.

typedef __bf16 bf16;
typedef __attribute__((ext_vector_type(8))) __bf16 bf16x8;
typedef __attribute__((ext_vector_type(4))) __bf16 bf16x4;
typedef __attribute__((ext_vector_type(4))) float f32x4;

#define B_  8
#define N_  2048
#define L_  4
#define D_  256
#define LD_ 1024
#define BK  32
#define NT  (N_ / BK)   // 64 K-tiles
#define NI  (NT / 2)    // 32 iterations

__device__ __forceinline__ void gl16(const char* g, char* l) {
  __builtin_amdgcn_global_load_lds((const __attribute__((address_space(1))) void*)g,
                                   (__attribute__((address_space(3))) void*)l, 16, 0, 0);
}

__device__ inline void cvt8(const float* __restrict__ s, bf16x8* o) {
  float4 x = ((const float4*)s)[0];
  float4 y = ((const float4*)s)[1];
  (*o)[0] = (bf16)x.x; (*o)[1] = (bf16)x.y; (*o)[2] = (bf16)x.z; (*o)[3] = (bf16)x.w;
  (*o)[4] = (bf16)y.x; (*o)[5] = (bf16)y.y; (*o)[6] = (bf16)y.z; (*o)[7] = (bf16)y.w;
}

// ---------------- kernel 1: HWT_T[b][l*256+e][m] = sum_d H[b][m][l][d]*W[e][d] ----
// LDS tiles XOR-swizzled (write slot (t&7)^((t>>3)&7); read slot ^ (row&7)).
__global__ __launch_bounds__(256) void hwt_kernel(const float* __restrict__ H,
                                                  const float* __restrict__ Wm,
                                                  bf16* __restrict__ outT) {
  const int bid = blockIdx.x;          // 8 * 64 * 2 = 1024 blocks
  const int b   = bid >> 7;
  const int rem = bid & 127;
  const int te  = rem & 1;
  const int tr  = rem >> 1;
  const int r0  = tr * 128;
  const int e0  = te * 128;

  __shared__ __attribute__((aligned(16))) char Ah[128 * 128];
  __shared__ __attribute__((aligned(16))) char Wt[128 * 128];

  const int t    = threadIdx.x;
  const int lane = t & 63;
  const int wave = t >> 6;
  const int wr = wave >> 1, wc = wave & 1;
  const int l15 = lane & 15;
  const int cg  = lane >> 4;

  const f32x4 zero = {0.f, 0.f, 0.f, 0.f};
  f32x4 acc[4][4];
  for (int m = 0; m < 4; ++m)
    for (int n = 0; n < 4; ++n) acc[m][n] = zero;

  const float* Hb = H + (size_t)b * (N_ * L_ * D_);
  const int mrow = t >> 3;          // 0..31
  const int colb = (t & 7) * 8;
  const int woff = (t >> 3) * 128 + (((t & 7) ^ ((t >> 3) & 7)) << 4);

  for (int k0 = 0; k0 < D_; k0 += 64) {
#pragma unroll
    for (int i = 0; i < 4; ++i) {
      const int r_local = mrow * 4 + i;     // l = i, m_local = mrow
      bf16x8 oa, ow;
      cvt8(Hb + (size_t)(r0 + r_local) * D_ + k0 + colb, &oa);
      const int erow = i * 32 + mrow;
      cvt8(Wm + (size_t)(e0 + erow) * D_ + k0 + colb, &ow);
      *(bf16x8*)(Ah + woff + i * 4096) = oa;
      *(bf16x8*)(Wt + woff + i * 4096) = ow;
    }
    __syncthreads();
#pragma unroll
    for (int kk = 0; kk < 2; ++kk) {
      bf16x8 af[4], bg[4];
#pragma unroll
      for (int m = 0; m < 4; ++m) {
        const int row = wr * 64 + m * 16 + l15;
        af[m] = *(const bf16x8*)&Ah[row * 128 + (((kk * 4 + cg) ^ (row & 7)) << 4)];
      }
#pragma unroll
      for (int n = 0; n < 4; ++n) {
        const int row = wc * 64 + n * 16 + l15;
        bg[n] = *(const bf16x8*)&Wt[row * 128 + (((kk * 4 + cg) ^ (row & 7)) << 4)];
      }
#pragma unroll
      for (int m = 0; m < 4; ++m)
#pragma unroll
        for (int n = 0; n < 4; ++n)
          acc[m][n] = __builtin_amdgcn_mfma_f32_16x16x32_bf16(af[m], bg[n], acc[m][n], 0, 0, 0);
    }
    __syncthreads();
  }

  bf16* ob = outT + (size_t)b * (LD_ * N_);
  const int m0 = tr * 32;
#pragma unroll
  for (int m16 = 0; m16 < 4; ++m16) {
    const int qrow = wr * 64 + m16 * 16 + (cg << 2);
    const int l  = qrow >> 5;
    const int ml = qrow & 31;
#pragma unroll
    for (int n = 0; n < 4; ++n) {
      const int e = e0 + wc * 64 + n * 16 + l15;
      bf16x4 v;
      v[0] = (bf16)acc[m16][n][0]; v[1] = (bf16)acc[m16][n][1];
      v[2] = (bf16)acc[m16][n][2]; v[3] = (bf16)acc[m16][n][3];
      *(bf16x4*)&ob[(size_t)(l * 256 + e) * N_ + m0 + ml] = v;
    }
  }
}

// ---------------- kernel 2: 256x256-tile BK=32 GEMM, fp32 A in LDS ----------------
// out[b][n][c] = relu(sum_m A[b][n][m] * HWT[b][c][m] + bias[c&255])
__global__ __launch_bounds__(512, 2) void gemm_f32a_kernel(
    const float* __restrict__ Af, const bf16* __restrict__ HWT,
    const float* __restrict__ bias, float* __restrict__ out) {

  // LDS: A fp32 [2][256][32] = 64 KB at 0; B bf16 [2][256][32] = 32 KB at 65536
  __shared__ __attribute__((aligned(128))) char smem[98304];
  char* const smA = smem;
  char* const smB = smem + 65536;

  // T1: 256 blocks % 8 == 0 -> xcd = batch
  const int bid = blockIdx.x;
  const int lg  = (bid & 7) * 32 + (bid >> 3);
  const int b   = lg >> 5;
  const int tn  = (lg >> 2) & 7;   // 8 row tiles of 256
  const int tc  = lg & 3;          // 4 col tiles of 256
  const int n0  = tn * 256;
  const int c0  = tc * 256;

  const int t    = threadIdx.x;
  const int lane = t & 63;
  const int w    = t >> 6;
  const int wm   = w >> 2;   // 0..1
  const int wn   = w & 3;    // 0..3
  const int l15  = lane & 15;
  const int cg   = lane >> 4;

  // ---- staging source pointers (pre-swizzled) ----
  const char* Ab = (const char*)(Af + (size_t)b * N_ * N_);
  const char* Hb = (const char*)(HWT + (size_t)b * LD_ * N_);
  // A: gl16 #j covers rows j*64 + (t>>3), slot u = t&7; source logical slot = u^(row&7)
  const char* pA0 = Ab + (size_t)(n0 + (t >> 3)) * (N_ * 4)
                    + (((t & 7) ^ ((t >> 3) & 7)) << 4);
  // B: gl16 #j covers rows j*128 + (t>>2), slot u = t&3; source logical slot = u^(row&3)
  const char* pB0 = Hb + (size_t)(c0 + (t >> 2)) * (N_ * 2)
                    + (((t & 3) ^ ((t >> 2) & 3)) << 4);
  char* const lA = smA + t * 16;
  char* const lB = smB + t * 16;

  // ---- fragment read address constants ----
  const int arow0 = wm * 128 + l15;           // + fm*16
  const int aslot0 = ((2 * cg) ^ (l15 & 7));  // physical slot of k-lo 16B
  const int aslot1 = aslot0 ^ 1;              // physical slot of k-hi 16B
  const int brow0 = wn * 64 + l15;            // + fn*16
  const int bslot = (cg ^ (l15 & 3));

#define STAGE6(buf, kt) do {                                                  \
    _Pragma("unroll")                                                         \
    for (int j_ = 0; j_ < 4; ++j_)                                            \
      gl16(pA0 + (size_t)j_ * (64 * N_ * 4) + (size_t)(kt) * 128,             \
           lA + (buf) * 32768 + j_ * 8192);                                   \
    _Pragma("unroll")                                                         \
    for (int j_ = 0; j_ < 2; ++j_)                                            \
      gl16(pB0 + (size_t)j_ * (128 * N_ * 2) + (size_t)(kt) * 64,             \
           lB + (buf) * 16384 + j_ * 8192);                                   \
  } while (0)

// read fp32 A frag (row arow0 + fm*16) from buf, convert to bf16x8
#define LDA_CVT(dst, buf, fm) do {                                            \
    const char* p_ = smA + (buf) * 32768 + (arow0 + (fm) * 16) * 128;         \
    f32x4 lo_ = *(const f32x4*)(p_ + (aslot0 << 4));                          \
    f32x4 hi_ = *(const f32x4*)(p_ + (aslot1 << 4));                          \
    dst[0] = (bf16)lo_[0]; dst[1] = (bf16)lo_[1];                             \
    dst[2] = (bf16)lo_[2]; dst[3] = (bf16)lo_[3];                             \
    dst[4] = (bf16)hi_[0]; dst[5] = (bf16)hi_[1];                             \
    dst[6] = (bf16)hi_[2]; dst[7] = (bf16)hi_[3];                             \
  } while (0)

#define LDB(buf, fn)                                                          \
  (*(const bf16x8*)(smB + (buf) * 16384 + (brow0 + (fn) * 16) * 64 +          \
                    (bslot << 4)))

// 16 MFMA: one mh half (fm base) x 4 fn, K=32
#define MFMA16(base, AF, BF) do {                                             \
    __builtin_amdgcn_s_setprio(1);                                            \
    _Pragma("unroll")                                                         \
    for (int fm_ = 0; fm_ < 4; ++fm_)                                         \
      _Pragma("unroll")                                                       \
      for (int fn_ = 0; fn_ < 4; ++fn_)                                       \
        acc[(base) + fm_][fn_] = __builtin_amdgcn_mfma_f32_16x16x32_bf16(     \
            AF[fm_], BF[fn_], acc[(base) + fm_][fn_], 0, 0, 0);               \
    __builtin_amdgcn_s_setprio(0);                                            \
  } while (0)

#define BARRIER() do { __builtin_amdgcn_s_barrier();                          \
                       asm volatile("" ::: "memory"); } while (0)
#define VM6_BAR() do {                                                        \
    asm volatile("s_waitcnt vmcnt(6)" ::: "memory");                          \
    __builtin_amdgcn_sched_barrier(0);                                        \
    BARRIER(); } while (0)

  f32x4 acc[8][4];
#pragma unroll
  for (int i_ = 0; i_ < 8; ++i_)
#pragma unroll
    for (int j_ = 0; j_ < 4; ++j_) acc[i_][j_] = (f32x4){0.f, 0.f, 0.f, 0.f};

  bf16x8 am[4];      // current A half (4 frags)
  bf16x8 bfr[4];     // current B K-tile (4 frags, reused across both mh)

  // prologue: buf0 <- kt0 (6 gl16 in flight)
  STAGE6(0, 0);

#pragma unroll 1
  for (int i = 0; i < NI; ++i) {
    const int kt1 = 2 * i + 1;
    const int kt2 = (2 * i + 2 < NT) ? 2 * i + 2 : NT - 2;  // tail clamp (data unused)

    // P1: stage buf1<-kt1; vmcnt(6) retires buf0's 6; BAR; read B(buf0)+A(buf0,mh0);
    //     MFMA mh0
    STAGE6(1, kt1);
    VM6_BAR();
#pragma unroll
    for (int fn = 0; fn < 4; ++fn) bfr[fn] = LDB(0, fn);
#pragma unroll
    for (int fm = 0; fm < 4; ++fm) LDA_CVT(am[fm], 0, fm);
    MFMA16(0, am, bfr);

    // P2: read A(buf0,mh1); MFMA mh1; BAR [all buf0 reads done -> P3 restage ok]
#pragma unroll
    for (int fm = 0; fm < 4; ++fm) LDA_CVT(am[fm], 0, 4 + fm);
    MFMA16(4, am, bfr);
    BARRIER();

    // P3: stage buf0<-kt2; vmcnt(6) retires buf1's 6; BAR; read B(buf1)+A(buf1,mh0);
    //     MFMA mh0
    STAGE6(0, kt2);
    VM6_BAR();
#pragma unroll
    for (int fn = 0; fn < 4; ++fn) bfr[fn] = LDB(1, fn);
#pragma unroll
    for (int fm = 0; fm < 4; ++fm) LDA_CVT(am[fm], 1, fm);
    MFMA16(0, am, bfr);

    // P4: read A(buf1,mh1); MFMA mh1; BAR [all buf1 reads done -> next P1 ok]
#pragma unroll
    for (int fm = 0; fm < 4; ++fm) LDA_CVT(am[fm], 1, 4 + fm);
    MFMA16(4, am, bfr);
    BARRIER();
  }

  // epilogue: + bias, relu, fp32 store
  float* ob = out + (size_t)b * N_ * LD_;
  const int orow0 = n0 + wm * 128 + cg * 4;
  const int ocol0 = c0 + wn * 64 + l15;
#pragma unroll
  for (int fm = 0; fm < 8; ++fm) {
    const int r = orow0 + fm * 16;
#pragma unroll
    for (int fn = 0; fn < 4; ++fn) {
      const int c = ocol0 + fn * 16;
      const float bv = bias[c & 255];
      const f32x4 v = acc[fm][fn];
#pragma unroll
      for (int j = 0; j < 4; ++j) {
        const float x = v[j] + bv;
        ob[(size_t)(r + j) * LD_ + c] = x > 0.f ? x : 0.f;
      }
    }
  }
#undef STAGE6
#undef LDA_CVT
#undef LDB
#undef MFMA16
#undef BARRIER
#undef VM6_BAR
}

extern "C" void kernel_launch(void* const* d_in, const int* in_sizes, int n_in,
                              void* d_out, int out_size, void* d_ws, size_t ws_size,
                              hipStream_t stream) {
  const float* H    = (const float*)d_in[0];   // prop_state (B,N,L,D)
  const float* A    = (const float*)d_in[1];   // (B,N,N)
  const float* Wm   = (const float*)d_in[2];   // (D,D)
  const float* bias = (const float*)d_in[3];   // (D,)
  float* out = (float*)d_out;

  const size_t hwt_bytes = (size_t)B_ * LD_ * N_ * sizeof(bf16);  // 33.5 MB
  if (ws_size < hwt_bytes) return;

  bf16* hwt = (bf16*)d_ws;

  hwt_kernel<<<dim3(1024), dim3(256), 0, stream>>>(H, Wm, hwt);
  gemm_f32a_kernel<<<dim3(256), dim3(512), 0, stream>>>(A, hwt, bias, out);
}